// Round 5
// baseline (1417.026 us; speedup 1.0000x reference)
//
#include <hip/hip_runtime.h>
#include <hip/hip_fp16.h>
#include <hip/hip_cooperative_groups.h>

namespace cg = cooperative_groups;

#define B_ 4
#define N_ 8192
#define D_ 4096
#define E_ 64
#define M_ (B_ * N_)          // 32768 tokens
#define NK 64                 // 64 K-chunks of 64

typedef _Float16 half8 __attribute__((ext_vector_type(8)));
typedef float f32x4 __attribute__((ext_vector_type(4)));

union H4 { _Float16 h[4]; uint2 u2; };

// ---------------------------------------------------------------------------
// w (fp32 [E][D]) -> w16 (f16 [E][D]) once; L2-resident thereafter.
// ---------------------------------------------------------------------------
__global__ __launch_bounds__(256) void convert_w(const float* __restrict__ w,
                                                 _Float16* __restrict__ w16) {
  const int i = (blockIdx.x * 256 + threadIdx.x) * 4;
  const float4 v = *(const float4*)&w[i];
  H4 h;
  h.h[0] = (_Float16)v.x; h.h[1] = (_Float16)v.y;
  h.h[2] = (_Float16)v.z; h.h[3] = (_Float16)v.w;
  *(uint2*)&w16[i] = h.u2;
}

// ---------------------------------------------------------------------------
// ONE cooperative kernel: GEMM (R2 structure) + in-register Sinkhorn.
// 512 blocks x 512 threads (2 blocks/CU, co-resident). Block owns 64 tokens.
// GEMM: reg-staged A (fp32->f16 cvt) + B (f16 from w16), dbuf LDS, one
// lgkm-only barrier per chunk, prefetch depth 2.
// Sinkhorn: t kept in VGPRs (lane=expert, 8 rows/lane); per iteration one
// block-reduce + device atomics + grid.sync(); output written once.
// ---------------------------------------------------------------------------
__global__ __launch_bounds__(512, 4) void fused(const float* __restrict__ x,
                                                const _Float16* __restrict__ w16,
                                                float* __restrict__ slots,
                                                float* __restrict__ out) {
  __shared__ _Float16 As[2][64 * 64];
  __shared__ _Float16 Bs[2][64 * 64];
  __shared__ float wsum[8][64];
  __shared__ float cbuf[64];
  float* tbuf = (float*)&As[0][0];        // 16 KiB alias (GEMM->sinkhorn handoff)

  const int tid = threadIdx.x;
  const int lane = tid & 63;
  const int wv = tid >> 6;                // 0..7
  const int l15 = lane & 15;
  const int lq = lane >> 4;               // 0..3
  const int rowBase = blockIdx.x * 64;
  const int b = rowBase >> 13;            // / N_
  const int wm = (wv >> 1) * 16;          // wave rows (16)
  const int wn = (wv & 1) * 32;           // wave cols (32)

  // staging map: srow 0..63, su 0..7 (16B unit); swizzle unit ^= srow&7
  const int srow = tid >> 3;
  const int su = tid & 7;
  const float* xs = x + (size_t)(rowBase + srow) * D_ + su * 8;
  const _Float16* ws = w16 + (size_t)srow * D_ + su * 8;
  const int sdst = srow * 64 + ((su ^ (srow & 7)) << 3);

  // loop-invariant fragment offsets
  const int arow = wm + l15;
  int aoff[2], boff[2][2];
#pragma unroll
  for (int ks = 0; ks < 2; ++ks)
    aoff[ks] = arow * 64 + (((ks * 4 + lq) ^ (arow & 7)) << 3);
#pragma unroll
  for (int ni = 0; ni < 2; ++ni) {
    const int bcol = wn + ni * 16 + l15;
#pragma unroll
    for (int ks = 0; ks < 2; ++ks)
      boff[ni][ks] = bcol * 64 + (((ks * 4 + lq) ^ (bcol & 7)) << 3);
  }

  f32x4 acc[2] = {};
  float4 pa0[2], pa1[2];
  half8 pb[2];

  // prologue: chunks 0,1 into register sets 0,1
  pa0[0] = *(const float4*)(xs);      pa1[0] = *(const float4*)(xs + 4);
  pb[0]  = *(const half8*)(ws);
  pa0[1] = *(const float4*)(xs + 64); pa1[1] = *(const float4*)(xs + 68);
  pb[1]  = *(const half8*)(ws + 64);

  for (int kc = 0; kc < NK; ++kc) {
    const int p = kc & 1;
    // stage chunk kc (vmcnt wait lands here, 3 newer loads still in flight)
    half8 hx;
    hx[0] = (_Float16)pa0[p].x; hx[1] = (_Float16)pa0[p].y;
    hx[2] = (_Float16)pa0[p].z; hx[3] = (_Float16)pa0[p].w;
    hx[4] = (_Float16)pa1[p].x; hx[5] = (_Float16)pa1[p].y;
    hx[6] = (_Float16)pa1[p].z; hx[7] = (_Float16)pa1[p].w;
    *(half8*)&As[p][sdst] = hx;
    *(half8*)&Bs[p][sdst] = pb[p];

    // prefetch chunk kc+2 into the just-freed register set
    if (kc + 2 < NK) {
      const int o = (kc + 2) * 64;
      pa0[p] = *(const float4*)(xs + o); pa1[p] = *(const float4*)(xs + o + 4);
      pb[p]  = *(const half8*)(ws + o);
    }

    // one barrier per chunk: drain LDS only, keep global loads in flight
    asm volatile("s_waitcnt lgkmcnt(0)" ::: "memory");
    __builtin_amdgcn_s_barrier();

    half8 a0  = *(const half8*)&As[p][aoff[0]];
    half8 a1  = *(const half8*)&As[p][aoff[1]];
    half8 b00 = *(const half8*)&Bs[p][boff[0][0]];
    half8 b01 = *(const half8*)&Bs[p][boff[0][1]];
    half8 b10 = *(const half8*)&Bs[p][boff[1][0]];
    half8 b11 = *(const half8*)&Bs[p][boff[1][1]];
    acc[0] = __builtin_amdgcn_mfma_f32_16x16x32_f16(a0, b00, acc[0], 0, 0, 0);
    acc[0] = __builtin_amdgcn_mfma_f32_16x16x32_f16(a1, b01, acc[0], 0, 0, 0);
    acc[1] = __builtin_amdgcn_mfma_f32_16x16x32_f16(a0, b10, acc[1], 0, 0, 0);
    acc[1] = __builtin_amdgcn_mfma_f32_16x16x32_f16(a1, b11, acc[1], 0, 0, 0);
  }

  __syncthreads();                         // all frag reads done; As free as tbuf

  // epilogue: t = log(clamp), into LDS tbuf; col-sum partials -> slots[0]
  float lsum[2] = {0.f, 0.f};
#pragma unroll
  for (int ni = 0; ni < 2; ++ni) {
#pragma unroll
    for (int r = 0; r < 4; ++r) {
      const float v = fmaxf(acc[ni][r], 1e-6f);
      tbuf[(wm + lq * 4 + r) * 64 + wn + ni * 16 + l15] = __logf(v);
      lsum[ni] += v;
    }
    float vv = lsum[ni];
    vv += __shfl_xor(vv, 16);
    vv += __shfl_xor(vv, 32);
    if (lq == 0) wsum[wv][ni * 16 + l15] = vv;
  }
  __syncthreads();
  if (tid < 64) {
    const int h = tid >> 5, idx = tid & 31;
    const float tot = wsum[h][idx] + wsum[2 + h][idx] + wsum[4 + h][idx] + wsum[6 + h][idx];
    atomicAdd(&slots[b * E_ + tid], tot);
  }

  // redistribute: lane = expert, 8 rows per lane
  float t[8];
#pragma unroll
  for (int r = 0; r < 8; ++r) t[r] = tbuf[(wv * 8 + r) * 64 + lane];

  __threadfence();
  cg::this_grid().sync();

  if (tid < 64) cbuf[tid] = __logf(atomicAdd(&slots[b * E_ + tid], 0.0f));
  __syncthreads();
  float C = cbuf[lane];

  for (int it = 1; it <= 8; ++it) {
    float q[8];
    float colacc = 0.f;
#pragma unroll
    for (int r = 0; r < 8; ++r) {
      const float p = __expf(t[r] - C);
      float s = p;
      s += __shfl_xor(s, 1);  s += __shfl_xor(s, 2);  s += __shfl_xor(s, 4);
      s += __shfl_xor(s, 8);  s += __shfl_xor(s, 16); s += __shfl_xor(s, 32);
      q[r] = p / s;
      colacc += q[r];
    }
    if (it < 8) {
      wsum[wv][lane] = colacc;
      __syncthreads();
      if (tid < 64) {
        float tot = 0.f;
#pragma unroll
        for (int w = 0; w < 8; ++w) tot += wsum[w][tid];
        atomicAdd(&slots[it * (B_ * E_) + b * E_ + tid], tot);
      }
      __threadfence();
      cg::this_grid().sync();
      if (tid < 64)
        cbuf[tid] = __logf(atomicAdd(&slots[it * (B_ * E_) + b * E_ + tid], 0.0f));
      __syncthreads();
      C += cbuf[lane];
    } else {
#pragma unroll
      for (int r = 0; r < 8; ++r)
        out[(size_t)(rowBase + wv * 8 + r) * 64 + lane] = q[r];
    }
  }
}

// ---------------------------------------------------------------------------
extern "C" void kernel_launch(void* const* d_in, const int* in_sizes, int n_in,
                              void* d_out, int out_size, void* d_ws, size_t ws_size,
                              hipStream_t stream) {
  (void)in_sizes; (void)n_in; (void)out_size; (void)ws_size;
  const float* x = (const float*)d_in[0];
  const float* w = (const float*)d_in[1];
  float* out = (float*)d_out;
  float* slots = (float*)d_ws;                      // [8][B_][E_] = 8 KiB
  _Float16* w16 = (_Float16*)((char*)d_ws + 8192);  // 512 KiB

  hipMemsetAsync(slots, 0, 8 * B_ * E_ * sizeof(float), stream);
  convert_w<<<(E_ * D_) / 1024, 256, 0, stream>>>(w, w16);
  void* args[] = { (void*)&x, (void*)&w16, (void*)&slots, (void*)&out };
  hipLaunchCooperativeKernel((void*)fused, dim3(M_ / 64), dim3(512), args, 0, stream);
}

// Round 7
// 253.626 us; speedup vs baseline: 5.5871x; 5.5871x over previous
//
#include <hip/hip_runtime.h>
#include <hip/hip_fp16.h>

#define B_ 4
#define N_ 8192
#define D_ 4096
#define E_ 64
#define M_ (B_ * N_)          // 32768 tokens
#define NK 64                 // 64 K-chunks of 64

typedef _Float16 half8 __attribute__((ext_vector_type(8)));
typedef float f32x4 __attribute__((ext_vector_type(4)));

union H4 { _Float16 h[4]; uint2 u2; };

// ---------------------------------------------------------------------------
// w (fp32 [E][D]) -> w16 (f16 [E][D]) once; L2-resident thereafter.
// ---------------------------------------------------------------------------
__global__ __launch_bounds__(256) void convert_w(const float* __restrict__ w,
                                                 _Float16* __restrict__ w16) {
  const int i = (blockIdx.x * 256 + threadIdx.x) * 4;
  const float4 v = *(const float4*)&w[i];
  H4 h;
  h.h[0] = (_Float16)v.x; h.h[1] = (_Float16)v.y;
  h.h[2] = (_Float16)v.z; h.h[3] = (_Float16)v.w;
  *(uint2*)&w16[i] = h.u2;
}

// ---------------------------------------------------------------------------
// GEMM: gates = x @ w16^T (f16 MFMA, fp32 accum).
// A: reg-staged through XOR-swizzled LDS (R2's proven path, dbuf, ONE
//    lgkm-only barrier per chunk; A prefetch stays in flight across it).
// B: fragments loaded DIRECT from L2-resident w16 (R3's proven addressing) —
//    no B staging: LDS ops 8->3 per wave-chunk, cvts 16->8 per thread-chunk.
// Load order: B(kc) issued first, then A(kc+1) prefetch => MFMA's B-wait is
// vmcnt(2), never draining the A prefetch.
// Epilogue: t0 = log(clamp(gate,1e-6)) -> d_out; col-sum partials -> slot0.
// ---------------------------------------------------------------------------
__global__ __launch_bounds__(512, 4) void gemm_log(const float* __restrict__ x,
                                                   const _Float16* __restrict__ w16,
                                                   float* __restrict__ t0,
                                                   float* __restrict__ slot0) {
  __shared__ _Float16 As[2][64 * 64];     // 16 KiB double buffer
  __shared__ float wsum[8][32];

  const int tid = threadIdx.x;
  const int lane = tid & 63;
  const int wv = tid >> 6;              // 0..7
  const int wm = (wv >> 1) * 16;        // wave row base (16 rows)
  const int wn = (wv & 1) * 32;         // wave col base (32 cols)
  const int l15 = lane & 15;
  const int lq = lane >> 4;             // k-quarter
  const int rowBase = blockIdx.x * 64;
  const int b = rowBase >> 13;          // / N_

  // A staging: thread -> (row 0..63, 16B-unit 0..7); unit swizzled by row&7
  const int sr = tid >> 3;
  const int su = tid & 7;
  const float* xs = x + (size_t)(rowBase + sr) * D_ + su * 8;
  const int sdst = sr * 64 + ((su ^ (sr & 7)) << 3);

  // A-fragment LDS offsets (loop-invariant)
  const int arow = wm + l15;
  const int aoff0 = arow * 64 + (((0 * 4 + lq) ^ (arow & 7)) << 3);
  const int aoff1 = arow * 64 + (((1 * 4 + lq) ^ (arow & 7)) << 3);

  // B-fragment global pointers: col = wn + ni*16 + l15, k = ks*32 + lq*8
  const _Float16* wB0 = w16 + (size_t)(wn + l15) * D_ + lq * 8;
  const _Float16* wB1 = w16 + (size_t)(wn + 16 + l15) * D_ + lq * 8;

  f32x4 acc0 = {}, acc1 = {};
  float4 xa, xb;
  half8 b00, b01, b10, b11;

  // prologue: A chunk 0 in flight
  xa = *(const float4*)(xs);
  xb = *(const float4*)(xs + 4);

  for (int kc = 0; kc < NK; ++kc) {
    const int cur = kc & 1;
    const int ko = kc * 64;

    // B fragments for THIS chunk (L1/L2-resident; issued early)
    b00 = *(const half8*)(wB0 + ko);
    b01 = *(const half8*)(wB0 + ko + 32);
    b10 = *(const half8*)(wB1 + ko);
    b11 = *(const half8*)(wB1 + ko + 32);

    // stage A(kc): compiler inserts vmcnt wait for xa/xb here (4 newer B
    // loads stay outstanding)
    half8 hx;
    hx[0] = (_Float16)xa.x; hx[1] = (_Float16)xa.y;
    hx[2] = (_Float16)xa.z; hx[3] = (_Float16)xa.w;
    hx[4] = (_Float16)xb.x; hx[5] = (_Float16)xb.y;
    hx[6] = (_Float16)xb.z; hx[7] = (_Float16)xb.w;
    *(half8*)&As[cur][sdst] = hx;

    // prefetch A(kc+1) — stays in flight across the barrier
    if (kc + 1 < NK) {
      xa = *(const float4*)(xs + ko + 64);
      xb = *(const float4*)(xs + ko + 68);
    }

    // ONE barrier per chunk: drain LDS only, keep global loads flying
    asm volatile("s_waitcnt lgkmcnt(0)" ::: "memory");
    __builtin_amdgcn_s_barrier();

    // A fragments + MFMA (B-wait lands at vmcnt(2): only A prefetch newer)
    half8 a0 = *(const half8*)&As[cur][aoff0];
    half8 a1 = *(const half8*)&As[cur][aoff1];
    acc0 = __builtin_amdgcn_mfma_f32_16x16x32_f16(a0, b00, acc0, 0, 0, 0);
    acc0 = __builtin_amdgcn_mfma_f32_16x16x32_f16(a1, b01, acc0, 0, 0, 0);
    acc1 = __builtin_amdgcn_mfma_f32_16x16x32_f16(a0, b10, acc1, 0, 0, 0);
    acc1 = __builtin_amdgcn_mfma_f32_16x16x32_f16(a1, b11, acc1, 0, 0, 0);
  }

  // epilogue: clamp, log -> t0, column sums -> slot0 (R2 verbatim)
  float ls0 = 0.f, ls1 = 0.f;
#pragma unroll
  for (int r = 0; r < 4; ++r) {
    const float v0 = fmaxf(acc0[r], 1e-6f);
    const float v1 = fmaxf(acc1[r], 1e-6f);
    const int grow = rowBase + wm + lq * 4 + r;
    t0[(size_t)grow * E_ + wn + l15] = __logf(v0);
    t0[(size_t)grow * E_ + wn + 16 + l15] = __logf(v1);
    ls0 += v0; ls1 += v1;
  }
  {
    float vv = ls0;
    vv += __shfl_xor(vv, 16); vv += __shfl_xor(vv, 32);
    if (lq == 0) wsum[wv][l15] = vv;
    vv = ls1;
    vv += __shfl_xor(vv, 16); vv += __shfl_xor(vv, 32);
    if (lq == 0) wsum[wv][16 + l15] = vv;
  }
  __syncthreads();
  if (tid < 64) {
    const int e = tid;
    const int half = e >> 5;
    const int idx = e & 31;
    const float tot = wsum[0 * 2 + half][idx] + wsum[1 * 2 + half][idx] +
                      wsum[2 * 2 + half][idx] + wsum[3 * 2 + half][idx];
    atomicAdd(&slot0[b * E_ + e], tot);
  }
}

// ---------------------------------------------------------------------------
// One Sinkhorn iteration (fused col+row pass), R2 verbatim:
//   C_it[e] = sum_j log(slots[j][b][e]); p = exp(t0 - C); s = row-sum(p);
//   last: out = p/s; else slots[it] += col-sum(p/s)
// ---------------------------------------------------------------------------
__global__ __launch_bounds__(256) void sinkhorn_iter(const float* __restrict__ t0,
                                                     float* __restrict__ slots,
                                                     float* __restrict__ out,
                                                     int it, int last) {
  const int tid = threadIdx.x;
  const int lane = tid & 63;
  const int wv = tid >> 6;
  const int b = blockIdx.x >> 8;
  const int chunk = blockIdx.x & 255;

  float C = __logf(slots[b * E_ + lane]);
  for (int j = 1; j < it; ++j) C += __logf(slots[j * (B_ * E_) + b * E_ + lane]);

  float colacc = 0.f;
  const int nbase = chunk * 32 + wv * 8;
#pragma unroll
  for (int i = 0; i < 8; ++i) {
    const int n = nbase + i;
    const float v = t0[((size_t)b * N_ + n) * E_ + lane];
    const float p = __expf(v - C);
    float s = p;
    s += __shfl_xor(s, 1);  s += __shfl_xor(s, 2);  s += __shfl_xor(s, 4);
    s += __shfl_xor(s, 8);  s += __shfl_xor(s, 16); s += __shfl_xor(s, 32);
    const float q = p / s;
    if (last) out[((size_t)b * N_ + n) * E_ + lane] = q;
    else      colacc += q;
  }
  if (!last) {
    __shared__ float wsum[4][64];
    wsum[wv][lane] = colacc;
    __syncthreads();
    if (tid < 64) {
      const float tot = wsum[0][tid] + wsum[1][tid] + wsum[2][tid] + wsum[3][tid];
      atomicAdd(&slots[it * (B_ * E_) + b * E_ + tid], tot);
    }
  }
}

// ---------------------------------------------------------------------------
extern "C" void kernel_launch(void* const* d_in, const int* in_sizes, int n_in,
                              void* d_out, int out_size, void* d_ws, size_t ws_size,
                              hipStream_t stream) {
  (void)in_sizes; (void)n_in; (void)out_size; (void)ws_size;
  const float* x = (const float*)d_in[0];
  const float* w = (const float*)d_in[1];
  float* out = (float*)d_out;                       // t0 lives here, final iter overwrites
  float* slots = (float*)d_ws;                      // [8][B_][E_] = 8 KiB
  _Float16* w16 = (_Float16*)((char*)d_ws + 8192);  // 512 KiB

  hipMemsetAsync(slots, 0, 8 * B_ * E_ * sizeof(float), stream);
  convert_w<<<(E_ * D_) / 1024, 256, 0, stream>>>(w, w16);
  gemm_log<<<M_ / 64, 512, 0, stream>>>(x, w16, out, slots);
  for (int it = 1; it <= 8; ++it)
    sinkhorn_iter<<<B_ * 256, 256, 0, stream>>>(out, slots, out, it, it == 8 ? 1 : 0);
}

// Round 8
// 241.550 us; speedup vs baseline: 5.8664x; 1.0500x over previous
//
#include <hip/hip_runtime.h>
#include <hip/hip_fp16.h>

#define B_ 4
#define N_ 8192
#define D_ 4096
#define E_ 64
#define M_ (B_ * N_)          // 32768 tokens
#define NK 64                 // 64 K-chunks of 64

typedef _Float16 half8 __attribute__((ext_vector_type(8)));
typedef float f32x4 __attribute__((ext_vector_type(4)));

union H4 { _Float16 h[4]; uint2 u2; };

// ---------------------------------------------------------------------------
// w (fp32 [E][D]) -> w16 (f16 [E][D]) once; L2-resident thereafter.
// ---------------------------------------------------------------------------
__global__ __launch_bounds__(256) void convert_w(const float* __restrict__ w,
                                                 _Float16* __restrict__ w16) {
  const int i = (blockIdx.x * 256 + threadIdx.x) * 4;
  const float4 v = *(const float4*)&w[i];
  H4 h;
  h.h[0] = (_Float16)v.x; h.h[1] = (_Float16)v.y;
  h.h[2] = (_Float16)v.z; h.h[3] = (_Float16)v.w;
  *(uint2*)&w16[i] = h.u2;
}

// ---------------------------------------------------------------------------
// GEMM: gates = x @ w16^T (f16 MFMA, fp32 accum).
// R2's proven staged structure + PREFETCH DEPTH 2 via named register sets
// (loads for chunk k issued at k-2 => ~2 iterations of latency slack; the
// lgkm-only barrier never drains them). No runtime-indexed registers.
// Epilogue: t0 = log(clamp(gate,1e-6)) -> d_out; col-sum partials -> slot0.
// ---------------------------------------------------------------------------
__global__ __launch_bounds__(512, 4) void gemm_log(const float* __restrict__ x,
                                                   const _Float16* __restrict__ w16,
                                                   float* __restrict__ t0,
                                                   float* __restrict__ slot0) {
  __shared__ _Float16 As[2][64 * 64];
  __shared__ _Float16 Bs[2][64 * 64];
  __shared__ float wsum[8][32];

  const int tid = threadIdx.x;
  const int lane = tid & 63;
  const int wv = tid >> 6;              // 0..7
  const int wm = (wv >> 1) * 16;        // wave row base (16 rows)
  const int wn = (wv & 1) * 32;         // wave col base (32 cols)
  const int l15 = lane & 15;
  const int lq = lane >> 4;             // k-quarter
  const int rowBase = blockIdx.x * 64;
  const int b = rowBase >> 13;          // / N_

  // staging map: srow 0..63, su 0..7 (16B unit); swizzle unit ^= srow&7
  const int sr = tid >> 3;
  const int su = tid & 7;
  const float* xs = x + (size_t)(rowBase + sr) * D_ + su * 8;
  const _Float16* ws = w16 + (size_t)sr * D_ + su * 8;
  const int sdst = sr * 64 + ((su ^ (sr & 7)) << 3);

  // loop-invariant fragment offsets
  const int arow = wm + l15;
  const int aoff0 = arow * 64 + ((lq ^ (arow & 7)) << 3);
  const int aoff1 = arow * 64 + (((4 + lq) ^ (arow & 7)) << 3);
  const int bcol0 = wn + l15;
  const int bcol1 = wn + 16 + l15;
  const int boff00 = bcol0 * 64 + ((lq ^ (bcol0 & 7)) << 3);
  const int boff01 = bcol0 * 64 + (((4 + lq) ^ (bcol0 & 7)) << 3);
  const int boff10 = bcol1 * 64 + ((lq ^ (bcol1 & 7)) << 3);
  const int boff11 = bcol1 * 64 + (((4 + lq) ^ (bcol1 & 7)) << 3);

  f32x4 acc0 = {}, acc1 = {};

  // named prefetch register sets (depth 2, NO runtime indexing)
  float4 ax0, ax1, cx0, cx1;
  half8 abw, cbw;

  auto body = [&](float4& px0, float4& px1, half8& pbw, int buf, int kpref) {
    // cvt + stage chunk (vmcnt wait for px*/pbw lands here — these loads were
    // issued TWO iterations ago; the newer set stays in flight)
    half8 hx;
    hx[0] = (_Float16)px0.x; hx[1] = (_Float16)px0.y;
    hx[2] = (_Float16)px0.z; hx[3] = (_Float16)px0.w;
    hx[4] = (_Float16)px1.x; hx[5] = (_Float16)px1.y;
    hx[6] = (_Float16)px1.z; hx[7] = (_Float16)px1.w;
    *(half8*)&As[buf][sdst] = hx;
    *(half8*)&Bs[buf][sdst] = pbw;
    // refill this register set with chunk kpref (2 ahead)
    if (kpref < NK) {
      const int o = kpref * 64;
      px0 = *(const float4*)(xs + o);
      px1 = *(const float4*)(xs + o + 4);
      pbw = *(const half8*)(ws + o);
    }
    // ONE barrier per chunk: drain LDS only, keep global loads flying
    asm volatile("s_waitcnt lgkmcnt(0)" ::: "memory");
    __builtin_amdgcn_s_barrier();
    half8 a0  = *(const half8*)&As[buf][aoff0];
    half8 a1  = *(const half8*)&As[buf][aoff1];
    half8 b00 = *(const half8*)&Bs[buf][boff00];
    half8 b01 = *(const half8*)&Bs[buf][boff01];
    half8 b10 = *(const half8*)&Bs[buf][boff10];
    half8 b11 = *(const half8*)&Bs[buf][boff11];
    acc0 = __builtin_amdgcn_mfma_f32_16x16x32_f16(a0, b00, acc0, 0, 0, 0);
    acc0 = __builtin_amdgcn_mfma_f32_16x16x32_f16(a1, b01, acc0, 0, 0, 0);
    acc1 = __builtin_amdgcn_mfma_f32_16x16x32_f16(a0, b10, acc1, 0, 0, 0);
    acc1 = __builtin_amdgcn_mfma_f32_16x16x32_f16(a1, b11, acc1, 0, 0, 0);
  };

  // prologue: chunks 0,1 in flight
  ax0 = *(const float4*)(xs);      ax1 = *(const float4*)(xs + 4);
  abw = *(const half8*)(ws);
  cx0 = *(const float4*)(xs + 64); cx1 = *(const float4*)(xs + 68);
  cbw = *(const half8*)(ws + 64);

  for (int kc = 0; kc < NK; kc += 2) {
    body(ax0, ax1, abw, 0, kc + 2);
    body(cx0, cx1, cbw, 1, kc + 3);
  }

  // epilogue: clamp, log -> t0, column sums -> slot0
  float ls0 = 0.f, ls1 = 0.f;
#pragma unroll
  for (int r = 0; r < 4; ++r) {
    const float v0 = fmaxf(acc0[r], 1e-6f);
    const float v1 = fmaxf(acc1[r], 1e-6f);
    const int grow = rowBase + wm + lq * 4 + r;
    t0[(size_t)grow * E_ + wn + l15] = __logf(v0);
    t0[(size_t)grow * E_ + wn + 16 + l15] = __logf(v1);
    ls0 += v0; ls1 += v1;
  }
  {
    float vv = ls0;
    vv += __shfl_xor(vv, 16); vv += __shfl_xor(vv, 32);
    if (lq == 0) wsum[wv][l15] = vv;
    vv = ls1;
    vv += __shfl_xor(vv, 16); vv += __shfl_xor(vv, 32);
    if (lq == 0) wsum[wv][16 + l15] = vv;
  }
  __syncthreads();
  if (tid < 64) {
    const int e = tid;
    const int half = e >> 5;      // which wn group
    const int idx = e & 31;
    const float tot = wsum[0 * 2 + half][idx] + wsum[1 * 2 + half][idx] +
                      wsum[2 * 2 + half][idx] + wsum[3 * 2 + half][idx];
    atomicAdd(&slot0[b * E_ + e], tot);
  }
}

// ---------------------------------------------------------------------------
// One Sinkhorn iteration (fused col+row pass), R2 verbatim:
//   C_it[e] = sum_j log(slots[j][b][e]); p = exp(t0 - C); s = row-sum(p);
//   last: out = p/s; else slots[it] += col-sum(p/s)
// ---------------------------------------------------------------------------
__global__ __launch_bounds__(256) void sinkhorn_iter(const float* __restrict__ t0,
                                                     float* __restrict__ slots,
                                                     float* __restrict__ out,
                                                     int it, int last) {
  const int tid = threadIdx.x;
  const int lane = tid & 63;
  const int wv = tid >> 6;
  const int b = blockIdx.x >> 8;
  const int chunk = blockIdx.x & 255;

  float C = __logf(slots[b * E_ + lane]);
  for (int j = 1; j < it; ++j) C += __logf(slots[j * (B_ * E_) + b * E_ + lane]);

  float colacc = 0.f;
  const int nbase = chunk * 32 + wv * 8;
#pragma unroll
  for (int i = 0; i < 8; ++i) {
    const int n = nbase + i;
    const float v = t0[((size_t)b * N_ + n) * E_ + lane];
    const float p = __expf(v - C);
    float s = p;
    s += __shfl_xor(s, 1);  s += __shfl_xor(s, 2);  s += __shfl_xor(s, 4);
    s += __shfl_xor(s, 8);  s += __shfl_xor(s, 16); s += __shfl_xor(s, 32);
    const float q = p / s;
    if (last) out[((size_t)b * N_ + n) * E_ + lane] = q;
    else      colacc += q;
  }
  if (!last) {
    __shared__ float wsum[4][64];
    wsum[wv][lane] = colacc;
    __syncthreads();
    if (tid < 64) {
      const float tot = wsum[0][tid] + wsum[1][tid] + wsum[2][tid] + wsum[3][tid];
      atomicAdd(&slots[it * (B_ * E_) + b * E_ + tid], tot);
    }
  }
}

// ---------------------------------------------------------------------------
extern "C" void kernel_launch(void* const* d_in, const int* in_sizes, int n_in,
                              void* d_out, int out_size, void* d_ws, size_t ws_size,
                              hipStream_t stream) {
  (void)in_sizes; (void)n_in; (void)out_size; (void)ws_size;
  const float* x = (const float*)d_in[0];
  const float* w = (const float*)d_in[1];
  float* out = (float*)d_out;                       // t0 lives here, final iter overwrites
  float* slots = (float*)d_ws;                      // [8][B_][E_] = 8 KiB
  _Float16* w16 = (_Float16*)((char*)d_ws + 8192);  // 512 KiB

  hipMemsetAsync(slots, 0, 8 * B_ * E_ * sizeof(float), stream);
  convert_w<<<(E_ * D_) / 1024, 256, 0, stream>>>(w, w16);
  gemm_log<<<M_ / 64, 512, 0, stream>>>(x, w16, out, slots);
  for (int it = 1; it <= 8; ++it)
    sinkhorn_iter<<<B_ * 256, 256, 0, stream>>>(out, slots, out, it, it == 8 ? 1 : 0);
}

// Round 9
// 218.430 us; speedup vs baseline: 6.4873x; 1.1058x over previous
//
#include <hip/hip_runtime.h>
#include <hip/hip_fp16.h>

#define B_ 4
#define N_ 8192
#define D_ 4096
#define E_ 64
#define M_ (B_ * N_)          // 32768 tokens
#define NK 64                 // 64 K-chunks of 64

typedef _Float16 half8 __attribute__((ext_vector_type(8)));
typedef float f32x4 __attribute__((ext_vector_type(4)));

union H4 { _Float16 h[4]; uint2 u2; };

// ---------------------------------------------------------------------------
// w (fp32 [E][D]) -> w16 (f16 [E][D]) once; L2-resident thereafter.
// ---------------------------------------------------------------------------
__global__ __launch_bounds__(256) void convert_w(const float* __restrict__ w,
                                                 _Float16* __restrict__ w16) {
  const int i = (blockIdx.x * 256 + threadIdx.x) * 4;
  const float4 v = *(const float4*)&w[i];
  H4 h;
  h.h[0] = (_Float16)v.x; h.h[1] = (_Float16)v.y;
  h.h[2] = (_Float16)v.z; h.h[3] = (_Float16)v.w;
  *(uint2*)&w16[i] = h.u2;
}

// ---------------------------------------------------------------------------
// GEMM: gates = x @ w16^T (f16 MFMA, fp32 accum).
// NEW AXIS: 32-row tile, 256 threads, grid 1024 => 4 independent blocks/CU
// (4 separate barrier groups per SIMD — stall overlap across blocks).
// Loop: named-set depth-2 prefetch, ONE lgkm-only barrier per chunk.
// A staged via XOR-swizzled LDS (fp32->f16 at stage); B staged from w16.
// Epilogue: t0 = log(clamp(gate,1e-6)) -> d_out; col-sum partials -> slot0.
// ---------------------------------------------------------------------------
__global__ __launch_bounds__(256, 4) void gemm_log(const float* __restrict__ x,
                                                   const _Float16* __restrict__ w16,
                                                   float* __restrict__ t0,
                                                   float* __restrict__ slot0) {
  __shared__ _Float16 As[2][32 * 64];     // 2 x 4 KiB
  __shared__ _Float16 Bs[2][64 * 64];     // 2 x 8 KiB
  __shared__ float wsum[4][32];

  const int tid = threadIdx.x;
  const int lane = tid & 63;
  const int wv = tid >> 6;              // 0..3
  const int wr = wv >> 1;               // row-half (16 rows)
  const int wc = wv & 1;                // col-half (32 cols)
  const int l15 = lane & 15;
  const int lq = lane >> 4;             // k-quarter
  const int rowBase = blockIdx.x * 32;
  const int b = rowBase >> 13;          // / N_

  // A staging: thread -> (row 0..31, 16B-unit 0..7); swizzle unit ^= row&7
  const int sar = tid >> 3;
  const int sau = tid & 7;
  const float* xs = x + (size_t)(rowBase + sar) * D_ + sau * 8;
  const int sdstA = sar * 64 + ((sau ^ (sar & 7)) << 3);

  // B staging: thread -> (erow 0..63, unit pair {up, up+1})
  const int sbr = tid >> 2;
  const int sbu = (tid & 3) * 2;
  const _Float16* ws2 = w16 + (size_t)sbr * D_ + sbu * 8;
  const int sdstB0 = sbr * 64 + ((sbu ^ (sbr & 7)) << 3);
  const int sdstB1 = sbr * 64 + (((sbu + 1) ^ (sbr & 7)) << 3);

  // fragment offsets (loop-invariant)
  const int arow = wr * 16 + l15;
  const int aoff0 = arow * 64 + ((lq ^ (arow & 7)) << 3);
  const int aoff1 = arow * 64 + (((4 + lq) ^ (arow & 7)) << 3);
  const int bcol0 = wc * 32 + l15;
  const int bcol1 = wc * 32 + 16 + l15;
  const int boff00 = bcol0 * 64 + ((lq ^ (bcol0 & 7)) << 3);
  const int boff01 = bcol0 * 64 + (((4 + lq) ^ (bcol0 & 7)) << 3);
  const int boff10 = bcol1 * 64 + ((lq ^ (bcol1 & 7)) << 3);
  const int boff11 = bcol1 * 64 + (((4 + lq) ^ (bcol1 & 7)) << 3);

  f32x4 acc0 = {}, acc1 = {};

  // named depth-2 prefetch register sets (no runtime indexing anywhere)
  float4 ax0, ax1, cx0, cx1;
  half8 ab0, ab1, cb0, cb1;

  auto body = [&](float4& px0, float4& px1, half8& pb0, half8& pb1,
                  int buf, int kpref) {
    // cvt + stage (vmcnt wait for px/pb lands here — issued 2 chunks ago)
    half8 hx;
    hx[0] = (_Float16)px0.x; hx[1] = (_Float16)px0.y;
    hx[2] = (_Float16)px0.z; hx[3] = (_Float16)px0.w;
    hx[4] = (_Float16)px1.x; hx[5] = (_Float16)px1.y;
    hx[6] = (_Float16)px1.z; hx[7] = (_Float16)px1.w;
    *(half8*)&As[buf][sdstA] = hx;
    *(half8*)&Bs[buf][sdstB0] = pb0;
    *(half8*)&Bs[buf][sdstB1] = pb1;
    // refill this set with chunk kpref (2 ahead) — flies across the barrier
    if (kpref < NK) {
      const int o = kpref * 64;
      px0 = *(const float4*)(xs + o);
      px1 = *(const float4*)(xs + o + 4);
      pb0 = *(const half8*)(ws2 + o);
      pb1 = *(const half8*)(ws2 + o + 8);
    }
    // ONE barrier per chunk: drain LDS only, keep global loads flying
    asm volatile("s_waitcnt lgkmcnt(0)" ::: "memory");
    __builtin_amdgcn_s_barrier();
    half8 a0  = *(const half8*)&As[buf][aoff0];
    half8 a1  = *(const half8*)&As[buf][aoff1];
    half8 b00 = *(const half8*)&Bs[buf][boff00];
    half8 b01 = *(const half8*)&Bs[buf][boff01];
    half8 b10 = *(const half8*)&Bs[buf][boff10];
    half8 b11 = *(const half8*)&Bs[buf][boff11];
    acc0 = __builtin_amdgcn_mfma_f32_16x16x32_f16(a0, b00, acc0, 0, 0, 0);
    acc0 = __builtin_amdgcn_mfma_f32_16x16x32_f16(a1, b01, acc0, 0, 0, 0);
    acc1 = __builtin_amdgcn_mfma_f32_16x16x32_f16(a0, b10, acc1, 0, 0, 0);
    acc1 = __builtin_amdgcn_mfma_f32_16x16x32_f16(a1, b11, acc1, 0, 0, 0);
  };

  // prologue: chunks 0,1 in flight
  ax0 = *(const float4*)(xs);      ax1 = *(const float4*)(xs + 4);
  ab0 = *(const half8*)(ws2);      ab1 = *(const half8*)(ws2 + 8);
  cx0 = *(const float4*)(xs + 64); cx1 = *(const float4*)(xs + 68);
  cb0 = *(const half8*)(ws2 + 64); cb1 = *(const half8*)(ws2 + 72);

  for (int kc = 0; kc < NK; kc += 2) {
    body(ax0, ax1, ab0, ab1, 0, kc + 2);
    body(cx0, cx1, cb0, cb1, 1, kc + 3);
  }

  // epilogue: clamp, log -> t0, column sums -> slot0
  float ls0 = 0.f, ls1 = 0.f;
#pragma unroll
  for (int r = 0; r < 4; ++r) {
    const float v0 = fmaxf(acc0[r], 1e-6f);
    const float v1 = fmaxf(acc1[r], 1e-6f);
    const int grow = rowBase + wr * 16 + lq * 4 + r;
    t0[(size_t)grow * E_ + wc * 32 + l15] = __logf(v0);
    t0[(size_t)grow * E_ + wc * 32 + 16 + l15] = __logf(v1);
    ls0 += v0; ls1 += v1;
  }
  {
    float vv = ls0;
    vv += __shfl_xor(vv, 16); vv += __shfl_xor(vv, 32);
    if (lq == 0) wsum[wv][l15] = vv;
    vv = ls1;
    vv += __shfl_xor(vv, 16); vv += __shfl_xor(vv, 32);
    if (lq == 0) wsum[wv][16 + l15] = vv;
  }
  __syncthreads();
  if (tid < 64) {
    const int e = tid;
    const int half = e >> 5;      // col-half -> waves {half, 2+half}
    const int idx = e & 31;
    const float tot = wsum[half][idx] + wsum[2 + half][idx];
    atomicAdd(&slot0[b * E_ + e], tot);
  }
}

// ---------------------------------------------------------------------------
// One Sinkhorn iteration (fused col+row pass), proven R2 structure:
//   C_it[e] = sum_j log(slots[j][b][e]); p = exp(t0 - C); s = row-sum(p);
//   last: out = p/s; else slots[it] += col-sum(p/s)
// ---------------------------------------------------------------------------
__global__ __launch_bounds__(256) void sinkhorn_iter(const float* __restrict__ t0,
                                                     float* __restrict__ slots,
                                                     float* __restrict__ out,
                                                     int it, int last) {
  const int tid = threadIdx.x;
  const int lane = tid & 63;
  const int wv = tid >> 6;
  const int b = blockIdx.x >> 8;
  const int chunk = blockIdx.x & 255;

  float C = __logf(slots[b * E_ + lane]);
  for (int j = 1; j < it; ++j) C += __logf(slots[j * (B_ * E_) + b * E_ + lane]);

  float colacc = 0.f;
  const int nbase = chunk * 32 + wv * 8;
#pragma unroll
  for (int i = 0; i < 8; ++i) {
    const int n = nbase + i;
    const float v = t0[((size_t)b * N_ + n) * E_ + lane];
    const float p = __expf(v - C);
    float s = p;
    s += __shfl_xor(s, 1);  s += __shfl_xor(s, 2);  s += __shfl_xor(s, 4);
    s += __shfl_xor(s, 8);  s += __shfl_xor(s, 16); s += __shfl_xor(s, 32);
    const float q = p / s;
    if (last) out[((size_t)b * N_ + n) * E_ + lane] = q;
    else      colacc += q;
  }
  if (!last) {
    __shared__ float wsum[4][64];
    wsum[wv][lane] = colacc;
    __syncthreads();
    if (tid < 64) {
      const float tot = wsum[0][tid] + wsum[1][tid] + wsum[2][tid] + wsum[3][tid];
      atomicAdd(&slots[it * (B_ * E_) + b * E_ + tid], tot);
    }
  }
}

// ---------------------------------------------------------------------------
extern "C" void kernel_launch(void* const* d_in, const int* in_sizes, int n_in,
                              void* d_out, int out_size, void* d_ws, size_t ws_size,
                              hipStream_t stream) {
  (void)in_sizes; (void)n_in; (void)out_size; (void)ws_size;
  const float* x = (const float*)d_in[0];
  const float* w = (const float*)d_in[1];
  float* out = (float*)d_out;                       // t0 lives here, final iter overwrites
  float* slots = (float*)d_ws;                      // [8][B_][E_] = 8 KiB
  _Float16* w16 = (_Float16*)((char*)d_ws + 8192);  // 512 KiB

  hipMemsetAsync(slots, 0, 8 * B_ * E_ * sizeof(float), stream);
  convert_w<<<(E_ * D_) / 1024, 256, 0, stream>>>(w, w16);
  gemm_log<<<M_ / 32, 256, 0, stream>>>(x, w16, out, slots);
  for (int it = 1; it <= 8; ++it)
    sinkhorn_iter<<<B_ * 256, 256, 0, stream>>>(out, slots, out, it, it == 8 ? 1 : 0);
}